// Round 5
// baseline (23.889 us; speedup 1.0000x reference)
//
#include <hip/hip_runtime.h>
#include <hip/hip_bf16.h>

#define EPS 1e-12f

constexpr int B = 32, P = 1000, H = 128, D = 64;
constexpr int TIL = 63;                 // ceil(P/16) 16-wide p tiles

typedef __attribute__((ext_vector_type(8))) short bf16x8;   // MFMA A/B frag
typedef __attribute__((ext_vector_type(4))) float f32x4;

__device__ __forceinline__ float fast_rcp(float x)  { return __builtin_amdgcn_rcpf(x); }
__device__ __forceinline__ float fast_sqrt(float x) { return __builtin_amdgcn_sqrtf(x); }

__device__ __forceinline__ int pk2(float x, float y) {
    union { __hip_bfloat162 t; int i; } u;
    u.t = __float22bfloat162_rn(make_float2(x, y));   // v_cvt_pk_bf16_f32
    return u.i;
}
__device__ __forceinline__ bf16x8 cvt8(f32x4 a, f32x4 b) {
    union { bf16x8 v; int i[4]; } u;
    u.i[0] = pk2(a.x, a.y); u.i[1] = pk2(a.z, a.w);
    u.i[2] = pk2(b.x, b.y); u.i[3] = pk2(b.z, b.w);
    return u.v;
}
__device__ __forceinline__ float sumsq16(f32x4 a, f32x4 b, f32x4 c, f32x4 d) {
    return (a.x*a.x + a.y*a.y + a.z*a.z + a.w*a.w)
         + (b.x*b.x + b.y*b.y + b.z*b.z + b.w*b.w)
         + (c.x*c.x + c.y*c.y + c.z*c.z + c.w*c.w)
         + (d.x*d.x + d.y*d.y + d.z*d.z + d.w*d.w);
}

// ---- Kernel A: hh[b][h] = ||h_row||^2, td[b][h] = w/sqrt(td+cutoff) into ws ----
__global__ __launch_bounds__(256)
void prep_kernel(const int* __restrict__ hist_items,
                 const float* __restrict__ hist_td,
                 const float* __restrict__ hist_w,
                 const float* __restrict__ emb_item,
                 const float* __restrict__ sc_cutoff,
                 float* __restrict__ ws)
{
    const int tid = threadIdx.x;
    const int row = blockIdx.x * 64 + (tid >> 2);   // (b,h) flat, 4 lanes per row
    const int q   = tid & 3;
    const int hidx = hist_items[row];
    const f32x4* rp = (const f32x4*)(emb_item + (size_t)hidx * D + q * 16);
    f32x4 v0 = rp[0], v1 = rp[1], v2 = rp[2], v3 = rp[3];
    float s = sumsq16(v0, v1, v2, v3);
    s += __shfl_xor(s, 1);
    s += __shfl_xor(s, 2);
    if (q == 0) {
        ws[row]         = s;
        ws[B * H + row] = hist_w[row] * __frsqrt_rn(hist_td[row] + *sc_cutoff);
    }
}

// ---- Kernel B: one (b, 16-p tile) per block; 4 waves split the 128 h rows ----
__global__ __launch_bounds__(256)
void main_kernel(const int* __restrict__ user_index,
                 const int* __restrict__ pred_items,
                 const int* __restrict__ hist_items,
                 const float* __restrict__ emb_user,
                 const float* __restrict__ emb_item,
                 const float* __restrict__ user_lamb,
                 const float* __restrict__ user_bias,
                 const float* __restrict__ item_bias,
                 const float* __restrict__ sc_global_lamb,
                 const float* __restrict__ sc_alpha,
                 const float* __restrict__ sc_beta,
                 const float* __restrict__ sc_gamma,
                 const float* __restrict__ sc_smooth,
                 const float* __restrict__ sc_force,
                 const float* __restrict__ ws,
                 float* __restrict__ out)
{
    __shared__ float red[4][16];

    const int b    = blockIdx.x / TIL;
    const int tile = blockIdx.x - b * TIL;
    const int tid  = threadIdx.x;
    const int w    = tid >> 6;
    const int lane = tid & 63;
    const int col  = lane & 15;         // p col / MFMA n (and A-row index for gathers)
    const int kg   = lane >> 4;         // k-group: d = kg*8..+7 (+32 for k-half 1)

    const int pg   = tile * 16 + col;
    const int pgc  = pg < P ? pg : P - 1;
    const int pidx = pred_items[b * P + pgc];

    const float* prow = emb_item + (size_t)pidx * D + kg * 8;
    f32x4 p0 = *(const f32x4*)(prow);
    f32x4 p1 = *(const f32x4*)(prow + 4);
    f32x4 p2 = *(const f32x4*)(prow + 32);
    f32x4 p3 = *(const f32x4*)(prow + 36);

    float pp = sumsq16(p0, p1, p2, p3);
    pp += __shfl_xor(pp, 16);
    pp += __shfl_xor(pp, 32);

    const bf16x8 bfr0 = cvt8(p0, p1);   // B frag k-half 0 (d 0..31)
    const bf16x8 bfr1 = cvt8(p2, p3);   // B frag k-half 1 (d 32..63)

    // dist_ui partial (f32 exact), wave 0 only
    const int uidx = user_index[b];
    float dpart = 0.f;
    if (w == 0) {
        const float* urow = emb_user + (size_t)uidx * D + kg * 8;
        f32x4 d0 = *(const f32x4*)(urow)      - p0;
        f32x4 d1 = *(const f32x4*)(urow + 4)  - p1;
        f32x4 d2 = *(const f32x4*)(urow + 32) - p2;
        f32x4 d3 = *(const f32x4*)(urow + 36) - p3;
        dpart = sumsq16(d0, d1, d2, d3);
        dpart += __shfl_xor(dpart, 16);
        dpart += __shfl_xor(dpart, 32);
    }

    // hh/td for this wave's 32 h rows: vector loads (L1/L2-hot from kernel A)
    const float* hhp = ws + b * H;
    const float* tdp = ws + B * H + b * H;
    const int t0 = w * 2;
    const f32x4 hhv0 = *(const f32x4*)(hhp + t0 * 16 + kg * 4);
    const f32x4 hhv1 = *(const f32x4*)(hhp + t0 * 16 + 16 + kg * 4);
    const f32x4 tdv0 = *(const f32x4*)(tdp + t0 * 16 + kg * 4);
    const f32x4 tdv1 = *(const f32x4*)(tdp + t0 * 16 + 16 + kg * 4);

    const float smooth = *sc_smooth;
    const float fs     = *sc_force * smooth;

    float pres = 0.f;
    #pragma unroll
    for (int ti = 0; ti < 2; ++ti) {
        const int t = t0 + ti;
        const int hidx = hist_items[b * H + t * 16 + col];
        const float* hrp = emb_item + (size_t)hidx * D + kg * 8;
        f32x4 a0 = *(const f32x4*)(hrp);
        f32x4 a1 = *(const f32x4*)(hrp + 4);
        f32x4 a2 = *(const f32x4*)(hrp + 32);
        f32x4 a3 = *(const f32x4*)(hrp + 36);
        const bf16x8 af0 = cvt8(a0, a1);
        const bf16x8 af1 = cvt8(a2, a3);
        f32x4 acc = {0.f, 0.f, 0.f, 0.f};
        acc = __builtin_amdgcn_mfma_f32_16x16x32_bf16(af0, bfr0, acc, 0, 0, 0);
        acc = __builtin_amdgcn_mfma_f32_16x16x32_bf16(af1, bfr1, acc, 0, 0, 0);
        const f32x4 hhv = ti ? hhv1 : hhv0;
        const f32x4 tdv = ti ? tdv1 : tdv0;
        #pragma unroll
        for (int j = 0; j < 4; ++j) {
            const float sq   = hhv[j] + pp - 2.f * acc[j];
            const float dist = fast_sqrt(fmaxf(sq, 0.f) + EPS);
            const float x    = smooth * fast_rcp(1.f + dist) - fs;
            pres += tdv[j] * fast_rcp(1.f + __expf(-x));
        }
    }
    pres += __shfl_xor(pres, 16);       // fold kg partitions -> sum over 32 rows
    pres += __shfl_xor(pres, 32);

    if (lane < 16) red[w][col] = pres;
    __syncthreads();

    if (w == 0 && lane < 16 && pg < P) {
        const float res = red[0][col] + red[1][col] + red[2][col] + red[3][col];
        const float inv_denom = 1.f + __expf(fs - smooth);
        const float lamb      = (*sc_global_lamb + user_lamb[uidx]) * inv_denom;
        const float dist_ui   = fast_sqrt(dpart + EPS);
        const float o = fmaxf(0.f, dist_ui - lamb * res);
        out[b * P + pg] = (*sc_alpha) * o + (*sc_beta) * o * o + (*sc_gamma)
                          + user_bias[uidx] + item_bias[pidx];
    }
}

extern "C" void kernel_launch(void* const* d_in, const int* in_sizes, int n_in,
                              void* d_out, int out_size, void* d_ws, size_t ws_size,
                              hipStream_t stream) {
    (void)in_sizes; (void)n_in; (void)ws_size; (void)out_size;
    float* ws = (float*)d_ws;
    prep_kernel<<<dim3((B * H) / 64), dim3(256), 0, stream>>>(
        (const int*)d_in[2], (const float*)d_in[3], (const float*)d_in[4],
        (const float*)d_in[6], (const float*)d_in[14], ws);
    main_kernel<<<dim3(B * TIL), dim3(256), 0, stream>>>(
        (const int*)d_in[0], (const int*)d_in[1], (const int*)d_in[2],
        (const float*)d_in[5], (const float*)d_in[6],
        (const float*)d_in[7], (const float*)d_in[8], (const float*)d_in[9],
        (const float*)d_in[10], (const float*)d_in[11], (const float*)d_in[12],
        (const float*)d_in[13], (const float*)d_in[15], (const float*)d_in[16],
        ws, (float*)d_out);
}

// Round 6
// 16.507 us; speedup vs baseline: 1.4472x; 1.4472x over previous
//
#include <hip/hip_runtime.h>
#include <hip/hip_bf16.h>

#define EPS 1e-12f

constexpr int B = 32, P = 1000, H = 128, D = 64;
constexpr int TIL = 63;                 // ceil(P/16) p-tiles of 16

typedef __attribute__((ext_vector_type(8))) short bf16x8;   // MFMA A/B frag
typedef __attribute__((ext_vector_type(4))) float f32x4;

__device__ __forceinline__ float fast_rcp(float x)  { return __builtin_amdgcn_rcpf(x); }
__device__ __forceinline__ float fast_sqrt(float x) { return __builtin_amdgcn_sqrtf(x); }

__device__ __forceinline__ int pk2(float x, float y) {
    union { __hip_bfloat162 t; int i; } u;
    u.t = __float22bfloat162_rn(make_float2(x, y));   // v_cvt_pk_bf16_f32
    return u.i;
}
__device__ __forceinline__ bf16x8 cvt8(f32x4 a, f32x4 b) {
    union { bf16x8 v; int i[4]; } u;
    u.i[0] = pk2(a.x, a.y); u.i[1] = pk2(a.z, a.w);
    u.i[2] = pk2(b.x, b.y); u.i[3] = pk2(b.z, b.w);
    return u.v;
}
__device__ __forceinline__ f32x4 scale4(f32x4 v, float s) {
    f32x4 r; r.x = v.x * s; r.y = v.y * s; r.z = v.z * s; r.w = v.w * s;
    return r;
}
__device__ __forceinline__ float sumsq16(f32x4 a, f32x4 b, f32x4 c, f32x4 d) {
    return (a.x*a.x + a.y*a.y + a.z*a.z + a.w*a.w)
         + (b.x*b.x + b.y*b.y + b.z*b.z + b.w*b.w)
         + (c.x*c.x + c.y*c.y + c.z*c.z + c.w*c.w)
         + (d.x*d.x + d.y*d.y + d.z*d.z + d.w*d.w);
}

// One wave per (b, 16-p tile): 16 p-cols x all 128 h rows, 8 MFMA-pair steps.
__global__ __launch_bounds__(64, 4)
void ex2vec_kernel(const int* __restrict__ user_index,
                   const int* __restrict__ pred_items,
                   const int* __restrict__ hist_items,
                   const float* __restrict__ hist_td,
                   const float* __restrict__ hist_w,
                   const float* __restrict__ emb_user,
                   const float* __restrict__ emb_item,
                   const float* __restrict__ user_lamb,
                   const float* __restrict__ user_bias,
                   const float* __restrict__ item_bias,
                   const float* __restrict__ sc_global_lamb,
                   const float* __restrict__ sc_alpha,
                   const float* __restrict__ sc_beta,
                   const float* __restrict__ sc_gamma,
                   const float* __restrict__ sc_cutoff,
                   const float* __restrict__ sc_smooth,
                   const float* __restrict__ sc_force,
                   float* __restrict__ out)
{
    const int b    = blockIdx.x / TIL;
    const int tile = blockIdx.x - b * TIL;
    const int lane = threadIdx.x;
    const int col  = lane & 15;         // p col / MFMA n; also A-row index for gathers
    const int kg   = lane >> 4;         // k-group: d = kg*8..+7 (+32 for k-half 1)

    const int pg   = tile * 16 + col;
    const int pgc  = pg < P ? pg : P - 1;
    const int pidx = pred_items[b * P + pgc];

    // ---- p fragments ----
    const float* prow = emb_item + (size_t)pidx * D + kg * 8;
    f32x4 p0 = *(const f32x4*)(prow);
    f32x4 p1 = *(const f32x4*)(prow + 4);
    f32x4 p2 = *(const f32x4*)(prow + 32);
    f32x4 p3 = *(const f32x4*)(prow + 36);

    // ---- hoist all h indices (enables early gather issue) ----
    int hidx[8];
    #pragma unroll
    for (int t = 0; t < 8; ++t) hidx[t] = hist_items[b * H + t * 16 + col];

    float pp = sumsq16(p0, p1, p2, p3);
    pp += __shfl_xor(pp, 16);
    pp += __shfl_xor(pp, 32);

    // B frags carry -2*p (exact bf16 scaling) so MFMA yields pp - 2*h.p directly
    const bf16x8 bfr0 = cvt8(scale4(p0, -2.f), scale4(p1, -2.f));
    const bf16x8 bfr1 = cvt8(scale4(p2, -2.f), scale4(p3, -2.f));

    const float cutoff = *sc_cutoff;
    const float smooth = *sc_smooth;
    const float fs     = *sc_force * smooth;

    float pres = 0.f;
    #pragma unroll
    for (int t = 0; t < 8; ++t) {
        const float* hrp = emb_item + (size_t)hidx[t] * D + kg * 8;
        f32x4 a0 = *(const f32x4*)(hrp);
        f32x4 a1 = *(const f32x4*)(hrp + 4);
        f32x4 a2 = *(const f32x4*)(hrp + 32);
        f32x4 a3 = *(const f32x4*)(hrp + 36);

        // hh for row (t*16 + col), full via kg-fold; td likewise per-row
        float s = sumsq16(a0, a1, a2, a3);
        s += __shfl_xor(s, 16);
        s += __shfl_xor(s, 32);
        const int r0 = b * H + t * 16 + col;
        const float tdc = hist_w[r0] * __frsqrt_rn(hist_td[r0] + cutoff);

        const bf16x8 af0 = cvt8(a0, a1);
        const bf16x8 af1 = cvt8(a2, a3);
        f32x4 acc = {pp, pp, pp, pp};       // C-init: + ||p||^2
        acc = __builtin_amdgcn_mfma_f32_16x16x32_bf16(af0, bfr0, acc, 0, 0, 0);
        acc = __builtin_amdgcn_mfma_f32_16x16x32_bf16(af1, bfr1, acc, 0, 0, 0);

        #pragma unroll
        for (int j = 0; j < 4; ++j) {
            const int src   = (kg << 2) | j;        // lane holding row t*16+kg*4+j stats
            const float hhv = __shfl(s, src);
            const float tdv = __shfl(tdc, src);
            const float sq   = acc[j] + hhv;        // hh + pp - 2 h.p
            const float dist = fast_sqrt(fmaxf(sq, 0.f) + EPS);
            const float x    = smooth * fast_rcp(1.f + dist) - fs;
            pres += tdv * fast_rcp(1.f + __expf(-x));
        }
    }
    pres += __shfl_xor(pres, 16);       // fold the 4 kg partitions -> all 128 h
    pres += __shfl_xor(pres, 32);

    // ---- dist_ui (f32 exact), cooperative over kg ----
    const int uidx = user_index[b];
    const float* urow = emb_user + (size_t)uidx * D + kg * 8;
    f32x4 d0 = *(const f32x4*)(urow)      - p0;
    f32x4 d1 = *(const f32x4*)(urow + 4)  - p1;
    f32x4 d2 = *(const f32x4*)(urow + 32) - p2;
    f32x4 d3 = *(const f32x4*)(urow + 36) - p3;
    float dp = sumsq16(d0, d1, d2, d3);
    dp += __shfl_xor(dp, 16);
    dp += __shfl_xor(dp, 32);

    if (lane < 16 && pg < P) {
        const float inv_denom = 1.f + __expf(fs - smooth);
        const float lamb      = (*sc_global_lamb + user_lamb[uidx]) * inv_denom;
        const float dist_ui   = fast_sqrt(dp + EPS);
        const float o = fmaxf(0.f, dist_ui - lamb * pres);
        out[b * P + pg] = (*sc_alpha) * o + (*sc_beta) * o * o + (*sc_gamma)
                          + user_bias[uidx] + item_bias[pidx];
    }
}

extern "C" void kernel_launch(void* const* d_in, const int* in_sizes, int n_in,
                              void* d_out, int out_size, void* d_ws, size_t ws_size,
                              hipStream_t stream) {
    (void)in_sizes; (void)n_in; (void)d_ws; (void)ws_size; (void)out_size;
    ex2vec_kernel<<<dim3(B * TIL), dim3(64), 0, stream>>>(
        (const int*)d_in[0],  (const int*)d_in[1],  (const int*)d_in[2],
        (const float*)d_in[3], (const float*)d_in[4],
        (const float*)d_in[5], (const float*)d_in[6],
        (const float*)d_in[7], (const float*)d_in[8], (const float*)d_in[9],
        (const float*)d_in[10], (const float*)d_in[11], (const float*)d_in[12],
        (const float*)d_in[13], (const float*)d_in[14], (const float*)d_in[15],
        (const float*)d_in[16], (float*)d_out);
}